// Round 6
// baseline (488.234 us; speedup 1.0000x reference)
//
#include <hip/hip_runtime.h>
#include <hip/hip_bf16.h>

// ---------------------------------------------------------------------------
// EncoderLayer (round 6): transposed-score MFMA flash attention (32x32x16,
// S^T = K*Q^T so softmax stats are lane-local; V pre-transposed by QKV GEMM;
// no barriers, no K/V LDS staging). MFMA GEMMs from round 5.
// B=2, S=4096, D=512, H=8, DK=64, DFF=2048.
// ---------------------------------------------------------------------------

typedef unsigned short u16;
typedef __attribute__((ext_vector_type(4))) u16 u16x4;
typedef __attribute__((ext_vector_type(8))) u16 u16x8;
typedef __attribute__((ext_vector_type(4))) float f32x4;
typedef __attribute__((ext_vector_type(16))) float f32x16;
typedef __attribute__((ext_vector_type(8))) short bf16x8;

#define CB 2
#define CS 4096
#define CD 512
#define CH 8
#define CDK 64
#define CDFF 2048
#define NXC ((size_t)CB * CS * CD)

__device__ __forceinline__ float bf2f(u16 u) {
    union { unsigned int i; float f; } c;
    c.i = ((unsigned int)u) << 16;
    return c.f;
}

__device__ __forceinline__ u16 f2bf(float f) {
    unsigned int x = __float_as_uint(f);
    unsigned int r = (x + 0x7fffu + ((x >> 16) & 1u)) >> 16;  // RNE
    return (u16)r;
}

// ---------------------------------------------------------------------------
// Dtype detection (bf16-packed vs fp32). flag=1 -> bf16.
// ---------------------------------------------------------------------------
__global__ void detect_dtype(const unsigned int* __restrict__ xw, int* __restrict__ flag) {
    __shared__ int red[256];
    int sane = 0;
    for (int i = threadIdx.x; i < 2048; i += 256) {
        unsigned int w = xw[i];
        unsigned int lo = w & 0xFFFFu;
        unsigned int e = (lo >> 7) & 0xFFu;
        if (lo == 0u || lo == 0x8000u || (e >= 96u && e <= 159u)) sane++;
    }
    red[threadIdx.x] = sane;
    __syncthreads();
    for (int s = 128; s > 0; s >>= 1) {
        if ((int)threadIdx.x < s) red[threadIdx.x] += red[threadIdx.x + s];
        __syncthreads();
    }
    if (threadIdx.x == 0) *flag = (red[0] >= 1843) ? 1 : 0;
}

__global__ __launch_bounds__(256) void convert_bf16(
    const void* __restrict__ src, u16* __restrict__ dst, int n,
    const int* __restrict__ flag)
{
    const bool isbf = (*flag != 0);
    int i = blockIdx.x * 256 + threadIdx.x;
    const int stride = gridDim.x * 256;
    if (isbf) {
        const u16* s = (const u16*)src;
        for (; i < n; i += stride) dst[i] = s[i];
    } else {
        const float* s = (const float*)src;
        for (; i < n; i += stride) dst[i] = f2bf(s[i]);
    }
}

struct SmallConv {
    const void* src[6];
    u16* dst[6];
    int n[6];
};

__global__ __launch_bounds__(256) void convert_small(SmallConv sc, const int* __restrict__ flag) {
    const bool isbf = (*flag != 0);
    for (int t = 0; t < 6; t++) {
        for (int i = threadIdx.x; i < sc.n[t]; i += 256) {
            if (isbf) sc.dst[t][i] = ((const u16*)sc.src[t])[i];
            else sc.dst[t][i] = f2bf(((const float*)sc.src[t])[i]);
        }
    }
}

// ---------------------------------------------------------------------------
// Mask bitmap: bits[b*64 + t] = ballot over 64 keys of tile t.
// ---------------------------------------------------------------------------
__global__ __launch_bounds__(256) void build_mask_bits(
    const int* __restrict__ mask, unsigned long long* __restrict__ bits)
{
    int w = blockIdx.x * 4 + (threadIdx.x >> 6);   // 0..127
    int lane = threadIdx.x & 63;
    int b = w >> 6, t = w & 63;
    int val = mask[b * CS + t * 64 + lane];
    unsigned long long bal = __ballot(val != 0);
    if (lane == 0) bits[w] = bal;
}

// ---------------------------------------------------------------------------
// Transposed convert: dst[c*R + r] = cvt(src[r*Cc + c]).  32x32 LDS tiles.
// ---------------------------------------------------------------------------
__global__ __launch_bounds__(256) void transpose_cvt(
    const void* __restrict__ src, u16* __restrict__ dst,
    int R, int Cc, const int* __restrict__ flag)
{
    __shared__ float t[32][33];
    const bool isbf = (*flag != 0);
    const int r0 = blockIdx.y * 32;
    const int c0 = blockIdx.x * 32;
    const int col = threadIdx.x & 31;
    const int row = threadIdx.x >> 5;
#pragma unroll
    for (int it = 0; it < 4; it++) {
        int rr = row + it * 8;
        float v;
        if (isbf) v = bf2f(((const u16*)src)[(size_t)(r0 + rr) * Cc + c0 + col]);
        else v = ((const float*)src)[(size_t)(r0 + rr) * Cc + c0 + col];
        t[rr][col] = v;
    }
    __syncthreads();
#pragma unroll
    for (int it = 0; it < 4; it++) {
        int rr = row + it * 8;
        dst[(size_t)(c0 + rr) * R + r0 + col] = f2bf(t[col][rr]);
    }
}

// ---------------------------------------------------------------------------
// MFMA GEMM: C[M,N] = A[M,K] * Bt[N,K]^T.  BM=BN=128, BK=32.
// F_SPLIT: n in [0,512)->q [B,H,S,DK]; [512,1024)->k same; [1024,1536)->
// v TRANSPOSED [B,H,DK,S] (packed u16x4 along s).
// ---------------------------------------------------------------------------
#define F_SPLIT 1
#define F_BIAS  2
#define F_RELU  4
#define LSTR 40

template <int FLAGS>
__global__ __launch_bounds__(256, 2) void gemm_mfma(
    const u16* __restrict__ A, const u16* __restrict__ Bt,
    const u16* __restrict__ bias, u16* __restrict__ C,
    int M, int N, int K)
{
    __shared__ u16 Asb[128 * LSTR];
    __shared__ u16 Bsb[128 * LSTR];

    const int tid = threadIdx.x;
    const int lane = tid & 63;
    const int wave = tid >> 6;
    const int lrow = lane & 15;
    const int quad = lane >> 4;
    const int wm = wave & 1;
    const int wn = wave >> 1;
    const int m0 = blockIdx.y * 128;
    const int n0 = blockIdx.x * 128;

    const int srow = tid >> 1;
    const int skc = (tid & 1) * 16;

    f32x4 acc[4][4];
#pragma unroll
    for (int i = 0; i < 4; i++)
#pragma unroll
        for (int j = 0; j < 4; j++) acc[i][j] = f32x4{0.f, 0.f, 0.f, 0.f};

    const u16* Ap = A + (size_t)(m0 + srow) * K + skc;
    const u16* Bp = Bt + (size_t)(n0 + srow) * K + skc;

    for (int k0 = 0; k0 < K; k0 += 32) {
        u16x8 a0 = *(const u16x8*)(Ap + k0);
        u16x8 a1 = *(const u16x8*)(Ap + k0 + 8);
        u16x8 b0 = *(const u16x8*)(Bp + k0);
        u16x8 b1 = *(const u16x8*)(Bp + k0 + 8);
        __syncthreads();
        *(u16x8*)&Asb[srow * LSTR + skc] = a0;
        *(u16x8*)&Asb[srow * LSTR + skc + 8] = a1;
        *(u16x8*)&Bsb[srow * LSTR + skc] = b0;
        *(u16x8*)&Bsb[srow * LSTR + skc + 8] = b1;
        __syncthreads();

        bf16x8 af[4], bfr[4];
#pragma unroll
        for (int i = 0; i < 4; i++)
            af[i] = *(const bf16x8*)&Asb[(wm * 64 + i * 16 + lrow) * LSTR + quad * 8];
#pragma unroll
        for (int j = 0; j < 4; j++)
            bfr[j] = *(const bf16x8*)&Bsb[(wn * 64 + j * 16 + lrow) * LSTR + quad * 8];
#pragma unroll
        for (int i = 0; i < 4; i++)
#pragma unroll
            for (int j = 0; j < 4; j++)
                acc[i][j] = __builtin_amdgcn_mfma_f32_16x16x32_bf16(
                    af[i], bfr[j], acc[i][j], 0, 0, 0);
    }

    const int mbase = m0 + wm * 64;
    const int nbase = n0 + wn * 64;
#pragma unroll
    for (int i = 0; i < 4; i++) {
#pragma unroll
        for (int j = 0; j < 4; j++) {
            const int n = nbase + j * 16 + lrow;
            if ((FLAGS & F_SPLIT) && ((nbase + j * 16) >> 9) == 2) {
                // v: transposed [B,H,DK,S], pack 4 consecutive s
                const int dk = n & 63;
                const int h = (n >> 6) & 7;
                const int sb = mbase + i * 16 + quad * 4;
                const int bb = sb >> 12;
                const int ss = sb & 4095;
                u16x4 ov;
#pragma unroll
                for (int r = 0; r < 4; r++) ov[r] = f2bf(acc[i][j][r]);
                *(u16x4*)&C[2 * NXC + (((size_t)(bb * CH + h)) * CDK + dk) * CS + ss] = ov;
            } else {
#pragma unroll
                for (int r = 0; r < 4; r++) {
                    const int m = mbase + i * 16 + quad * 4 + r;
                    float val = acc[i][j][r];
                    if (FLAGS & F_BIAS) val += bf2f(bias[n]);
                    if (FLAGS & F_RELU) val = fmaxf(val, 0.f);
                    if (FLAGS & F_SPLIT) {
                        const int proj = n >> 9;       // 0=q,1=k
                        const int d = n & 511;
                        const int h = d >> 6;
                        const int dk = d & 63;
                        const int bb = m >> 12;
                        const int ss = m & 4095;
                        C[proj * NXC + (((size_t)(bb * CH + h)) * CS + ss) * CDK + dk] = f2bf(val);
                    } else {
                        C[(size_t)m * N + n] = f2bf(val);
                    }
                }
            }
        }
    }
}

// ---------------------------------------------------------------------------
// Transposed-score MFMA flash attention.
// grid (CS/128, B*H), 256 thr = 4 waves; wave owns 32 queries.
// Per 64-key tile: S^T = K*Q^T via 32x32x16 MFMA (C cols = queries ->
// softmax stats lane-local, 1 shuffle per reduction); P^T through wave-
// private LDS; O^T += V^T * P^T with V^T streamed from HBM [B,H,DK,S].
// Layouts (32x32x16): A[m=lane&31][k=8*(lane>>5)+j], B likewise for cols;
// C/D: col=lane&31, row=(reg&3)+8*(reg>>2)+4*(lane>>5).
// ---------------------------------------------------------------------------
#define PSTR 72

__global__ __launch_bounds__(256, 2) void mfma_attn2(
    const u16* __restrict__ Qb, const u16* __restrict__ Kb,
    const u16* __restrict__ Vt, const unsigned long long* __restrict__ bits,
    u16* __restrict__ ctx)
{
    __shared__ u16 Pbuf[4][32 * PSTR];

    const int tid = threadIdx.x;
    const int lane = tid & 63;
    const int wave = tid >> 6;
    const int qcol = lane & 31;
    const int hf = lane >> 5;

    const int bh = blockIdx.y;
    const int b = bh >> 3;
    const int h = bh & 7;
    const int q0 = blockIdx.x * 128 + wave * 32;

    const float SC = 0.125f * 1.44269504088896340736f;  // 1/sqrt(64) * log2(e)

    // Q B-frags (loop-invariant): B[k=dk][n=query]
    bf16x8 bq[4];
    const u16* qp = Qb + ((size_t)bh * CS + q0 + qcol) * CDK + hf * 8;
#pragma unroll
    for (int c = 0; c < 4; c++) bq[c] = *(const bf16x8*)(qp + c * 16);

    f32x16 ot[2];
#pragma unroll
    for (int dt = 0; dt < 2; dt++)
#pragma unroll
        for (int i = 0; i < 16; i++) ot[dt][i] = 0.f;
    float m = -1e30f, l = 0.f;

    u16* Pw = &Pbuf[wave][0];
    const u16* kbase = Kb + (size_t)bh * CS * CDK;
    const u16* vbase = Vt + (size_t)bh * CDK * CS;
    const unsigned long long* bp = bits + b * 64;

    for (int t = 0; t < CS; t += 64) {
        // ---- S^T = K * Q^T (2 key m-tiles x 4 dk chunks)
        f32x16 s[2];
#pragma unroll
        for (int mt = 0; mt < 2; mt++) {
#pragma unroll
            for (int i = 0; i < 16; i++) s[mt][i] = 0.f;
            const u16* kp = kbase + (size_t)(t + mt * 32 + qcol) * CDK + hf * 8;
#pragma unroll
            for (int c = 0; c < 4; c++) {
                bf16x8 ak = *(const bf16x8*)(kp + c * 16);
                s[mt] = __builtin_amdgcn_mfma_f32_32x32x16_bf16(ak, bq[c], s[mt], 0, 0, 0);
            }
        }
        // ---- scale (+ mask via bitmap; uniform fast path when all-ones)
        const unsigned long long bm = bp[t >> 6];
        if (bm == ~0ull) {
#pragma unroll
            for (int mt = 0; mt < 2; mt++)
#pragma unroll
                for (int i = 0; i < 16; i++) s[mt][i] *= SC;
        } else {
#pragma unroll
            for (int mt = 0; mt < 2; mt++)
#pragma unroll
                for (int i = 0; i < 16; i++) {
                    const int key = (i & 3) + 8 * (i >> 2) + 4 * hf + 32 * mt;
                    float v = s[mt][i] * SC;
                    s[mt][i] = ((bm >> key) & 1ull) ? v : -1e9f;
                }
        }
        // ---- online softmax, lane-local (log2 domain)
        float tm = s[0][0];
#pragma unroll
        for (int i = 1; i < 16; i++) tm = fmaxf(tm, s[0][i]);
#pragma unroll
        for (int i = 0; i < 16; i++) tm = fmaxf(tm, s[1][i]);
        tm = fmaxf(tm, __shfl_xor(tm, 32, 64));
        const float mn = fmaxf(m, tm);
        const float alpha = exp2f(m - mn);
        m = mn;
        float rs = 0.f;
#pragma unroll
        for (int mt = 0; mt < 2; mt++)
#pragma unroll
            for (int i = 0; i < 16; i++) {
                float p = exp2f(s[mt][i] - mn);
                s[mt][i] = p;
                rs += p;
            }
        rs += __shfl_xor(rs, 32, 64);
        l = l * alpha + rs;
#pragma unroll
        for (int dt = 0; dt < 2; dt++)
#pragma unroll
            for (int i = 0; i < 16; i++) ot[dt][i] *= alpha;
        // ---- P^T -> wave-private LDS (b64 packed: 4 consecutive keys/reg-group)
#pragma unroll
        for (int mt = 0; mt < 2; mt++)
#pragma unroll
            for (int g = 0; g < 4; g++) {
                u16x4 pk;
#pragma unroll
                for (int e = 0; e < 4; e++) pk[e] = f2bf(s[mt][g * 4 + e]);
                *(u16x4*)&Pw[qcol * PSTR + 8 * g + 4 * hf + 32 * mt] = pk;
            }
        // ---- O^T += V^T * P^T
        bf16x8 pf[4];
#pragma unroll
        for (int c = 0; c < 4; c++)
            pf[c] = *(const bf16x8*)&Pw[qcol * PSTR + c * 16 + 8 * hf];
#pragma unroll
        for (int dt = 0; dt < 2; dt++) {
            const u16* vp = vbase + (size_t)(dt * 32 + qcol) * CS + t + hf * 8;
#pragma unroll
            for (int c = 0; c < 4; c++) {
                bf16x8 av = *(const bf16x8*)(vp + c * 16);
                ot[dt] = __builtin_amdgcn_mfma_f32_32x32x16_bf16(av, pf[c], ot[dt], 0, 0, 0);
            }
        }
    }

    // ---- epilogue: O^T cols = queries (lane-local l); rows = dk
    const float inv = 1.f / l;
    u16* cp = ctx + ((size_t)b * CS + q0 + qcol) * CD + h * CDK;
#pragma unroll
    for (int dt = 0; dt < 2; dt++)
#pragma unroll
        for (int g = 0; g < 4; g++) {
            u16x4 ov;
#pragma unroll
            for (int e = 0; e < 4; e++) ov[e] = f2bf(ot[dt][g * 4 + e] * inv);
            *(u16x4*)(cp + 8 * g + 4 * hf + 32 * dt) = ov;
        }
}

// ---------------------------------------------------------------------------
// Residual + LayerNorm (unchanged).
// ---------------------------------------------------------------------------
__global__ __launch_bounds__(256) void ln_kernel(
    const u16* __restrict__ xa, const u16* __restrict__ xb,
    const u16* __restrict__ g, const u16* __restrict__ be,
    u16* __restrict__ outb, float* __restrict__ outf,
    const int* __restrict__ flag)
{
    const int lane = threadIdx.x & 63;
    const int wave = threadIdx.x >> 6;
    const size_t row = (size_t)blockIdx.x * 4 + wave;
    const int c0 = lane * 8;

    u16x8 av = *(const u16x8*)(xa + row * CD + c0);
    u16x8 bv = *(const u16x8*)(xb + row * CD + c0);

    float v[8];
    float s1 = 0.f, s2 = 0.f;
#pragma unroll
    for (int e = 0; e < 8; e++) {
        v[e] = bf2f(av[e]) + bf2f(bv[e]);
        s1 += v[e];
        s2 += v[e] * v[e];
    }
#pragma unroll
    for (int off = 32; off > 0; off >>= 1) {
        s1 += __shfl_xor(s1, off, 64);
        s2 += __shfl_xor(s2, off, 64);
    }
    const float mu = s1 * (1.f / CD);
    const float var = fmaxf(s2 * (1.f / CD) - mu * mu, 0.f);
    const float r = rsqrtf(var + 1e-5f);

    u16x8 gv = *(const u16x8*)(g + c0);
    u16x8 ev = *(const u16x8*)(be + c0);
    float res[8];
#pragma unroll
    for (int e = 0; e < 8; e++)
        res[e] = (v[e] - mu) * r * bf2f(gv[e]) + bf2f(ev[e]);

    const int flg = *flag;
    const bool f32out = (outf != nullptr) && (flg == 0);
    if (f32out) {
        float4 o0 = make_float4(res[0], res[1], res[2], res[3]);
        float4 o1 = make_float4(res[4], res[5], res[6], res[7]);
        *(float4*)(outf + row * CD + c0) = o0;
        *(float4*)(outf + row * CD + c0 + 4) = o1;
    } else {
        u16x8 ov;
#pragma unroll
        for (int e = 0; e < 8; e++) ov[e] = f2bf(res[e]);
        *(u16x8*)(outb + row * CD + c0) = ov;
    }
}

// ---------------------------------------------------------------------------

extern "C" void kernel_launch(void* const* d_in, const int* in_sizes, int n_in,
                              void* d_out, int out_size, void* d_ws, size_t ws_size,
                              hipStream_t stream)
{
    const void* x_raw   = d_in[0];
    const int*  mask    = (const int*)d_in[1];
    const void* wq_raw  = d_in[2];
    const void* wk_raw  = d_in[3];
    const void* wv_raw  = d_in[4];
    const void* wo_raw  = d_in[5];
    const void* w1_raw  = d_in[6];
    const void* b1_raw  = d_in[7];
    const void* w2_raw  = d_in[8];
    const void* b2_raw  = d_in[9];
    const void* g1_raw  = d_in[10];
    const void* be1_raw = d_in[11];
    const void* g2_raw  = d_in[12];
    const void* be2_raw = d_in[13];

    const size_t NX = NXC;
    const size_t WSZ = (size_t)CD * CD;
    const size_t W1SZ = (size_t)CD * CDFF;

    u16* ws = (u16*)d_ws;
    int* flag = (int*)d_ws;                               // bytes [0,4)
    unsigned long long* bits = (unsigned long long*)(ws + 512);  // bytes [1024,2048)
    u16* base = ws + 1024;
    u16* xc  = base;
    u16* q   = base + 1 * NX;
    u16* k   = base + 2 * NX;
    u16* v   = base + 3 * NX;   // holds V^T [B,H,DK,S]
    u16* ctx = base + 4 * NX;
    u16* att = base + 5 * NX;
    u16* x1  = base + 6 * NX;
    u16* ffo = base + 7 * NX;
    u16* ffh = base + 8 * NX;   // 4*NX
    u16* wt  = base + 12 * NX;
    u16* wqkvT = wt;            // [1536][512]
    u16* woT = wqkvT + 3 * WSZ;
    u16* w1T = woT + WSZ;
    u16* w2T = w1T + W1SZ;
    u16* b1c = w2T + W1SZ;
    u16* b2c = b1c + CDFF;
    u16* g1c = b2c + CD;
    u16* be1c = g1c + CD;
    u16* g2c = be1c + CD;
    u16* be2c = g2c + CD;
    u16* wend = be2c + CD;

    const size_t need = (size_t)(wend - ws) * sizeof(u16);
    if (ws_size < need) return;
    (void)k;

    detect_dtype<<<1, 256, 0, stream>>>((const unsigned int*)x_raw, flag);

    convert_bf16<<<1024, 256, 0, stream>>>(x_raw, xc, (int)NX, flag);
    build_mask_bits<<<32, 256, 0, stream>>>(mask, bits);

    transpose_cvt<<<dim3(CD / 32, CD / 32), 256, 0, stream>>>(wq_raw, wqkvT, CD, CD, flag);
    transpose_cvt<<<dim3(CD / 32, CD / 32), 256, 0, stream>>>(wk_raw, wqkvT + WSZ, CD, CD, flag);
    transpose_cvt<<<dim3(CD / 32, CD / 32), 256, 0, stream>>>(wv_raw, wqkvT + 2 * WSZ, CD, CD, flag);
    transpose_cvt<<<dim3(CD / 32, CD / 32), 256, 0, stream>>>(wo_raw, woT, CD, CD, flag);
    transpose_cvt<<<dim3(CDFF / 32, CD / 32), 256, 0, stream>>>(w1_raw, w1T, CD, CDFF, flag);
    transpose_cvt<<<dim3(CD / 32, CDFF / 32), 256, 0, stream>>>(w2_raw, w2T, CDFF, CD, flag);

    SmallConv sc;
    sc.src[0] = b1_raw;  sc.dst[0] = b1c;  sc.n[0] = CDFF;
    sc.src[1] = b2_raw;  sc.dst[1] = b2c;  sc.n[1] = CD;
    sc.src[2] = g1_raw;  sc.dst[2] = g1c;  sc.n[2] = CD;
    sc.src[3] = be1_raw; sc.dst[3] = be1c; sc.n[3] = CD;
    sc.src[4] = g2_raw;  sc.dst[4] = g2c;  sc.n[4] = CD;
    sc.src[5] = be2_raw; sc.dst[5] = be2c; sc.n[5] = CD;
    convert_small<<<1, 256, 0, stream>>>(sc, flag);

    const int M = CB * CS;  // 8192

    gemm_mfma<F_SPLIT><<<dim3(1536 / 128, M / 128), 256, 0, stream>>>(
        xc, wqkvT, nullptr, q, M, 1536, CD);

    mfma_attn2<<<dim3(CS / 128, CB * CH), 256, 0, stream>>>(q, k, v, bits, ctx);

    gemm_mfma<0><<<dim3(CD / 128, M / 128), 256, 0, stream>>>(
        ctx, woT, nullptr, att, M, CD, CD);

    ln_kernel<<<dim3(M / 4), 256, 0, stream>>>(xc, att, g1c, be1c, x1, nullptr, flag);

    gemm_mfma<F_BIAS | F_RELU><<<dim3(CDFF / 128, M / 128), 256, 0, stream>>>(
        x1, w1T, b1c, ffh, M, CDFF, CD);
    gemm_mfma<F_BIAS><<<dim3(CD / 128, M / 128), 256, 0, stream>>>(
        ffh, w2T, b2c, ffo, M, CD, CDFF);

    ln_kernel<<<dim3(M / 4), 256, 0, stream>>>(x1, ffo, g2c, be2c,
                                               (u16*)d_out, (float*)d_out, flag);
}